// Round 15
// baseline (467.572 us; speedup 1.0000x reference)
//
#include <hip/hip_runtime.h>

#define NN 100000
#define NE 1600000
#define ET 1700000        // NE + NN self-loops
#define NEG 0.2f
#define FNEG 3.4e38f
#define NBSC 98           // scan blocks: ceil(NN/1024)
#define GEMM1_NB 1563     // ceil(NN/64)
#define PE_NB 6641        // ceil(ET/256)
#define FATA_NB 8305      // 5 * 1661 covers 4:1 interleave of PE_NB:GEMM1_NB
#define FILL_CH 425000    // ET/4 (divisible by 8)
#define DCAP 64           // staged-alpha degree cap (max random deg ~45)

// ---------------- workspace layout (bytes) ----------------
#define SRC_OFF   0ULL
#define DST_OFF   6800000ULL
#define RP_OFF    13600000ULL         // rowptr (NN+1)*4
#define CSR_OFF   14400128ULL         // ET*4
#define W1F_OFF   21200128ULL         // 65536  (16mf x 4kk x 64lane x 8 bf16)
#define W2F_OFF   21265664ULL         // 16384
#define W3F_OFF   21282048ULL         // 3072
#define SC_OFF    21285120ULL         // 1024 (block sums)
#define H_OFF     21286144ULL         // h1 as fp8 e4m3: N*256 = 25.6MB
#define H2B_OFF   72486144ULL         // h2b 6.4MB (bf16)
#define H3B_OFF   88486144ULL         // h3b 8MB (bf16)
#define AS3_OFF   123686144ULL        // layer-3 a_s: 400KB
#define AD3_OFF   124086144ULL        // layer-3 a_d: 400KB
#define ASN_OFF   150886144ULL        // layer-1 a_s: 3.2MB
#define ADN_OFF   154086144ULL        // layer-1 a_d: 3.2MB
#define AS2_OFF   157286144ULL        // layer-2 a_s: 400KB
#define AD2_OFF   157686144ULL        // layer-2 a_d: 400KB
#define CNT_OFF   158086144ULL        // region-replicated histogram 8*NN*4 = 3.2MB
#define RANK_OFF  164486144ULL        // per-edge rank within replica: ET*4
#define WS_NEED   171286144ULL

typedef short bf16x8 __attribute__((ext_vector_type(8)));
typedef float f32x4 __attribute__((ext_vector_type(4)));
typedef float f32x2 __attribute__((ext_vector_type(2)));

__device__ __forceinline__ float lrelu(float x) { return x > 0.f ? x : NEG * x; }
__device__ __forceinline__ float b2f(unsigned short u) {
  return __uint_as_float(((unsigned)u) << 16);
}
__device__ __forceinline__ unsigned short f2bu(float f) {   // RNE f32->bf16
  unsigned u = __float_as_uint(f);
  return (unsigned short)((u + 0x7FFFu + ((u >> 16) & 1u)) >> 16);
}

__global__ __launch_bounds__(256) void k_sentinel(float* out, int n) {
  int i = blockIdx.x * 256 + threadIdx.x;
  if (i < n) out[i] = 12345.0f;
}

// Pre-arrange W1/W2/W3 (f32) into MFMA A-fragment order as bf16.
__global__ __launch_bounds__(256) void k_prep_w(const float* __restrict__ W1,
                                                const float* __restrict__ W2,
                                                const float* __restrict__ W3,
                                                unsigned short* __restrict__ W1f,
                                                unsigned short* __restrict__ W2f,
                                                unsigned short* __restrict__ W3f) {
  int idx = blockIdx.x * 256 + threadIdx.x;
  if (idx < 4096) {                       // W1: 16 mf x 4 kk
    int fg = idx >> 6, lane = idx & 63;
    int mf = fg >> 2, kk = fg & 3;
    int c = mf * 16 + (lane & 15), k0 = kk * 32 + (lane >> 4) * 8;
    unsigned short* o = W1f + idx * 8;
    #pragma unroll
    for (int j = 0; j < 8; ++j) o[j] = f2bu(W1[(k0 + j) * 256 + c]);
  } else if (idx < 5120) {                // W2: 2 mf x 8 kk
    int t = idx - 4096;
    int fg = t >> 6, lane = t & 63;
    int mf = fg >> 3, kk = fg & 7;
    int c = mf * 16 + (lane & 15), k0 = kk * 32 + (lane >> 4) * 8;
    unsigned short* o = W2f + t * 8;
    #pragma unroll
    for (int j = 0; j < 8; ++j) o[j] = f2bu(W2[(k0 + j) * 32 + c]);
  } else if (idx < 5312) {                // W3: 3 mf x 1 kk (pad ch>=40 with 0)
    int t = idx - 5120;
    int mf = t >> 6, lane = t & 63;
    int c = mf * 16 + (lane & 15), k0 = (lane >> 4) * 8;
    unsigned short* o = W3f + t * 8;
    #pragma unroll
    for (int j = 0; j < 8; ++j) o[j] = (c < 40) ? f2bu(W3[(k0 + j) * 40 + c]) : 0;
  }
}

// Fat kernel A: prep_edges (+region-replicated deg count, rank capture)
// interleaved 4:1 with gemm1 (h1 = x@W1 -> fp8 e4m3 + fused a_s/a_d in f32).
__global__ __launch_bounds__(256) void k_fatA(const int* __restrict__ raw,
                                              int* __restrict__ src,
                                              int* __restrict__ dst,
                                              int* __restrict__ cnt8,
                                              int* __restrict__ rank,
                                              const float* __restrict__ x,
                                              const bf16x8* __restrict__ W1f,
                                              const float* __restrict__ as1,
                                              const float* __restrict__ ad1,
                                              unsigned char* __restrict__ h8,
                                              float* __restrict__ a_s,
                                              float* __restrict__ a_d) {
  __shared__ __align__(16) unsigned short xs[64 * 128];
  __shared__ float asL[256], adL[256];
  const int bid = blockIdx.x;
  const int grp = bid / 5, rem = bid - grp * 5;
  const int tid = threadIdx.x;

  if (rem != 4) {                               // ---- prep_edges ----
    int pe = grp * 4 + rem;
    if (pe >= PE_NB) return;
    bool is64 = true;
    #pragma unroll
    for (int i = 1; i < 32; i += 2) is64 = is64 && (raw[i] == 0);
    long long e = (long long)pe * 256 + tid;
    if (e >= ET) return;
    int s, d;
    if (e < NE) {
      if (is64) {
        const long long* r = (const long long*)raw;
        s = (int)r[e];
        d = (int)r[NE + e];
      } else {
        s = raw[e];
        d = raw[NE + e];
      }
    } else {
      s = d = (int)(e - NE);
    }
    src[e] = s;
    dst[e] = d;
    // 8 region-replicated counters (replica = e&7 = tid&7): distinct lines/node
    rank[e] = atomicAdd(&cnt8[(tid & 7) * NN + d], 1);
    return;
  }

  // ---- gemm1 ----
  if (grp >= GEMM1_NB) return;
  const int n0 = grp * 64;
  asL[tid] = as1[tid];
  adL[tid] = ad1[tid];
  for (int j = tid; j < 2048; j += 256) {       // stage x -> bf16 LDS
    int r = j >> 5;
    int c4 = (j & 31) << 2;
    long long row = n0 + r; if (row >= NN) row = NN - 1;
    float4 v = *(const float4*)(x + row * 128 + c4);
    unsigned short* p = &xs[r * 128 + c4];
    p[0] = f2bu(v.x); p[1] = f2bu(v.y); p[2] = f2bu(v.z); p[3] = f2bu(v.w);
  }
  __syncthreads();
  const int w = tid >> 6, lane = tid & 63;
  const int nloc = w * 16 + (lane & 15);
  const int node = n0 + nloc;
  bf16x8 bfr[4];
  #pragma unroll
  for (int kk = 0; kk < 4; ++kk)
    bfr[kk] = *(const bf16x8*)&xs[nloc * 128 + kk * 32 + (lane >> 4) * 8];
  const int ch_base = (lane >> 4) * 4;
  float sA[8] = {}, sD[8] = {};
  #pragma unroll
  for (int mf = 0; mf < 16; ++mf) {
    f32x4 acc = {0.f, 0.f, 0.f, 0.f};
    #pragma unroll
    for (int kk = 0; kk < 4; ++kk) {
      bf16x8 af = W1f[(mf * 4 + kk) * 64 + lane];
      acc = __builtin_amdgcn_mfma_f32_16x16x32_bf16(af, bfr[kk], acc, 0, 0, 0);
    }
    const float* av = &asL[mf * 16 + ch_base];
    const float* dv = &adL[mf * 16 + ch_base];
    float ps = acc[0] * av[0] + acc[1] * av[1] + acc[2] * av[2] + acc[3] * av[3];
    float pd = acc[0] * dv[0] + acc[1] * dv[1] + acc[2] * dv[2] + acc[3] * dv[3];
    ps += __shfl_xor(ps, 16); ps += __shfl_xor(ps, 32);
    pd += __shfl_xor(pd, 16); pd += __shfl_xor(pd, 32);
    sA[mf >> 1] += ps; sD[mf >> 1] += pd;
    if (node < NN) {
      int w01 = __builtin_amdgcn_cvt_pk_fp8_f32(acc[0], acc[1], 0, false);
      int w0123 = __builtin_amdgcn_cvt_pk_fp8_f32(acc[2], acc[3], w01, true);
      *(unsigned*)&h8[(unsigned)(node * 256 + mf * 16 + ch_base)] = (unsigned)w0123;
    }
  }
  if (lane < 16 && node < NN) {
    #pragma unroll
    for (int hd = 0; hd < 8; ++hd) {
      a_s[node * 8 + hd] = sA[hd];
      a_d[node * 8 + hd] = sD[hd];
    }
  }
}

// Block-level inclusive scan over node degrees, folding the 8 region replicas.
__global__ __launch_bounds__(1024) void k_scan_a(int* __restrict__ cnt8,
                                                 int* __restrict__ rowptr,
                                                 int* __restrict__ bsum) {
  __shared__ int wsum[16];
  const int lane = threadIdx.x & 63, wid = threadIdx.x >> 6;
  int i = blockIdx.x * 1024 + threadIdx.x;
  int x = 0;
  if (i < NN) {
    int run = 0;
    #pragma unroll
    for (int k = 0; k < 8; ++k) {
      int c = cnt8[k * NN + i];
      cnt8[k * NN + i] = run;        // exclusive prefix (per-replica base)
      run += c;
    }
    x = run;
  }
  int inc = x;
  #pragma unroll
  for (int off = 1; off < 64; off <<= 1) {
    int t = __shfl_up(inc, off);
    if (lane >= off) inc += t;
  }
  if (lane == 63) wsum[wid] = inc;
  __syncthreads();
  if (wid == 0) {
    int w = (lane < 16) ? wsum[lane] : 0;
    #pragma unroll
    for (int off = 1; off < 16; off <<= 1) {
      int t = __shfl_up(w, off);
      if (lane >= off) w += t;
    }
    if (lane < 16) wsum[lane] = w;
  }
  __syncthreads();
  int base = wid ? wsum[wid - 1] : 0;
  if (i < NN) rowptr[i + 1] = base + inc;
  if (threadIdx.x == 1023) bsum[blockIdx.x] = base + inc;
}

// Exclusive scan of NBSC block sums (in place).
__global__ __launch_bounds__(128) void k_scan_b(int* __restrict__ bsum) {
  __shared__ int w0tot;
  int tid = threadIdx.x;
  int v = (tid < NBSC) ? bsum[tid] : 0;
  int inc = v;
  #pragma unroll
  for (int off = 1; off < 64; off <<= 1) {
    int t = __shfl_up(inc, off);
    if ((tid & 63) >= off) inc += t;
  }
  if (tid == 63) w0tot = inc;
  __syncthreads();
  if (tid >= 64) inc += w0tot;
  if (tid < NBSC) bsum[tid] = inc - v;
}

__global__ __launch_bounds__(1024) void k_scan_c(int* __restrict__ rowptr,
                                                 const int* __restrict__ bsum) {
  int i = blockIdx.x * 1024 + threadIdx.x;
  if (i < NN) rowptr[i + 1] += bsum[blockIdx.x];
  if (i == 0) rowptr[0] = 0;
}

// Atomic-free CSR fill: slot = rowptr[d] + prefix8[e&7][d] + rank[e].
__global__ __launch_bounds__(256) void k_fill_nr(const int* __restrict__ src,
                                                 const int* __restrict__ dst,
                                                 const int* __restrict__ rank,
                                                 const int* __restrict__ cnt8,
                                                 const int* __restrict__ rowptr,
                                                 int* __restrict__ csr) {
  int gid = blockIdx.x * 256 + threadIdx.x;
  if (gid >= FILL_CH) return;
  const int h = gid & 7;                 // FILL_CH % 8 == 0 -> e&7 == gid&7
  int e0 = gid, e1 = gid + FILL_CH, e2 = gid + 2 * FILL_CH, e3 = gid + 3 * FILL_CH;
  int d0 = dst[e0], d1 = dst[e1], d2 = dst[e2], d3 = dst[e3];
  int r0 = rank[e0], r1 = rank[e1], r2 = rank[e2], r3 = rank[e3];
  int s0 = src[e0], s1 = src[e1], s2 = src[e2], s3 = src[e3];
  int p0 = cnt8[h * NN + d0], p1 = cnt8[h * NN + d1];
  int p2 = cnt8[h * NN + d2], p3 = cnt8[h * NN + d3];
  int b0 = rowptr[d0], b1 = rowptr[d1], b2 = rowptr[d2], b3 = rowptr[d3];
  csr[b0 + p0 + r0] = s0;
  csr[b1 + p1 + r1] = s1;
  csr[b2 + p2 + r2] = s2;
  csr[b3 + p3 + r3] = s3;
}

// Layer-1: FUSED softmax + fp8 gather + bias + ELU + gemm2 (+layer-2 a_s/a_d
// epilogue into fresh buffers). 1024 threads = 16 waves = 16 nodes/block.
// Pass 1 computes per-head max/sum; alpha is STAGED ONCE per (edge,head) in
// LDS f32 (deg<=DCAP; rare fallback recomputes) -> no 8x redundant exp.
__global__ __launch_bounds__(1024) void k_gather1f(const int* __restrict__ rowptr,
                                                   const int* __restrict__ csr,
                                                   const float* __restrict__ as1n,
                                                   const float* __restrict__ ad1n,
                                                   const unsigned char* __restrict__ h8,
                                                   const float* __restrict__ b,
                                                   const bf16x8* __restrict__ W2f,
                                                   const float* __restrict__ as2,
                                                   const float* __restrict__ ad2,
                                                   unsigned short* __restrict__ h2,
                                                   float* __restrict__ a_s2o,
                                                   float* __restrict__ a_d2o) {
  __shared__ __align__(16) unsigned short xs[16 * 256];   // 8KB
  __shared__ float alds[16 * DCAP * 8];                   // 32KB staged alpha
  const int tid = threadIdx.x;
  const int w = tid >> 6, lane = tid & 63;
  const int n0 = blockIdx.x * 16;
  const int node = n0 + w;
  const int beg = __builtin_amdgcn_readfirstlane(rowptr[node]);
  const int end = __builtin_amdgcn_readfirstlane(rowptr[node + 1]);

  // ---- pass 1: per-head online max/sum (hd = lane&7, edge-group = lane>>3) ----
  const int hd = lane & 7;
  const int eg = lane >> 3;
  const float adv1 = ad1n[node * 8 + hd];
  float mx = -FNEG, sm = 0.f;
  for (int i = beg + eg; i < end; i += 8) {
    float v = lrelu(as1n[csr[i] * 8 + hd] + adv1);
    float nm = fmaxf(mx, v);
    sm = sm * __expf(mx - nm) + __expf(v - nm);
    mx = nm;
  }
  #pragma unroll
  for (int off = 8; off < 64; off <<= 1) {
    float mo = __shfl_xor(mx, off);
    float so = __shfl_xor(sm, off);
    float nm = fmaxf(mx, mo);
    sm = sm * __expf(mx - nm) + so * __expf(mo - nm);
    mx = nm;
  }
  const float rdenh = 1.0f / sm;          // per-head denom (valid on all lanes)

  // ---- pass 1b: stage alpha once per (edge, head) ----
  float* al = &alds[w * (DCAP * 8)];
  const int dcap = (end - beg <= DCAP) ? end : beg + DCAP;
  for (int i = beg + eg; i < dcap; i += 8) {
    float v = lrelu(as1n[csr[i] * 8 + hd] + adv1);
    al[(i - beg) * 8 + hd] = __expf(v - mx) * rdenh;
  }

  // per-lane head constants for pass 2 / fallback
  const int hd2 = lane >> 3;
  const float m2 = __shfl(mx, hd2);
  const float rden2 = __shfl(rdenh, hd2);
  const float adv2 = ad1n[node * 8 + hd2];

  // ---- pass 2: fp8 gather with staged alpha, 8-deep MLP ----
  const unsigned l4 = lane * 4;
  float4 acc = {0.f, 0.f, 0.f, 0.f};
  int i = beg;
  for (; i + 8 <= dcap; i += 8) {
    int s0 = __builtin_amdgcn_readfirstlane(csr[i]);
    int s1 = __builtin_amdgcn_readfirstlane(csr[i + 1]);
    int s2 = __builtin_amdgcn_readfirstlane(csr[i + 2]);
    int s3 = __builtin_amdgcn_readfirstlane(csr[i + 3]);
    int s4 = __builtin_amdgcn_readfirstlane(csr[i + 4]);
    int s5 = __builtin_amdgcn_readfirstlane(csr[i + 5]);
    int s6 = __builtin_amdgcn_readfirstlane(csr[i + 6]);
    int s7 = __builtin_amdgcn_readfirstlane(csr[i + 7]);
    unsigned w0 = *(const unsigned*)(h8 + ((unsigned)(s0 << 8) + l4));
    unsigned w1 = *(const unsigned*)(h8 + ((unsigned)(s1 << 8) + l4));
    unsigned w2 = *(const unsigned*)(h8 + ((unsigned)(s2 << 8) + l4));
    unsigned w3 = *(const unsigned*)(h8 + ((unsigned)(s3 << 8) + l4));
    unsigned w4 = *(const unsigned*)(h8 + ((unsigned)(s4 << 8) + l4));
    unsigned w5 = *(const unsigned*)(h8 + ((unsigned)(s5 << 8) + l4));
    unsigned w6 = *(const unsigned*)(h8 + ((unsigned)(s6 << 8) + l4));
    unsigned w7 = *(const unsigned*)(h8 + ((unsigned)(s7 << 8) + l4));
    int o0 = (i - beg) * 8 + hd2;
    float a0 = al[o0 +  0], a1 = al[o0 +  8], a2 = al[o0 + 16], a3 = al[o0 + 24];
    float a4 = al[o0 + 32], a5 = al[o0 + 40], a6 = al[o0 + 48], a7 = al[o0 + 56];
    f32x2 lo, hi;
    lo = __builtin_amdgcn_cvt_pk_f32_fp8(w0, false); hi = __builtin_amdgcn_cvt_pk_f32_fp8(w0, true);
    acc.x += a0 * lo[0]; acc.y += a0 * lo[1]; acc.z += a0 * hi[0]; acc.w += a0 * hi[1];
    lo = __builtin_amdgcn_cvt_pk_f32_fp8(w1, false); hi = __builtin_amdgcn_cvt_pk_f32_fp8(w1, true);
    acc.x += a1 * lo[0]; acc.y += a1 * lo[1]; acc.z += a1 * hi[0]; acc.w += a1 * hi[1];
    lo = __builtin_amdgcn_cvt_pk_f32_fp8(w2, false); hi = __builtin_amdgcn_cvt_pk_f32_fp8(w2, true);
    acc.x += a2 * lo[0]; acc.y += a2 * lo[1]; acc.z += a2 * hi[0]; acc.w += a2 * hi[1];
    lo = __builtin_amdgcn_cvt_pk_f32_fp8(w3, false); hi = __builtin_amdgcn_cvt_pk_f32_fp8(w3, true);
    acc.x += a3 * lo[0]; acc.y += a3 * lo[1]; acc.z += a3 * hi[0]; acc.w += a3 * hi[1];
    lo = __builtin_amdgcn_cvt_pk_f32_fp8(w4, false); hi = __builtin_amdgcn_cvt_pk_f32_fp8(w4, true);
    acc.x += a4 * lo[0]; acc.y += a4 * lo[1]; acc.z += a4 * hi[0]; acc.w += a4 * hi[1];
    lo = __builtin_amdgcn_cvt_pk_f32_fp8(w5, false); hi = __builtin_amdgcn_cvt_pk_f32_fp8(w5, true);
    acc.x += a5 * lo[0]; acc.y += a5 * lo[1]; acc.z += a5 * hi[0]; acc.w += a5 * hi[1];
    lo = __builtin_amdgcn_cvt_pk_f32_fp8(w6, false); hi = __builtin_amdgcn_cvt_pk_f32_fp8(w6, true);
    acc.x += a6 * lo[0]; acc.y += a6 * lo[1]; acc.z += a6 * hi[0]; acc.w += a6 * hi[1];
    lo = __builtin_amdgcn_cvt_pk_f32_fp8(w7, false); hi = __builtin_amdgcn_cvt_pk_f32_fp8(w7, true);
    acc.x += a7 * lo[0]; acc.y += a7 * lo[1]; acc.z += a7 * hi[0]; acc.w += a7 * hi[1];
  }
  for (; i < dcap; ++i) {
    int s0 = __builtin_amdgcn_readfirstlane(csr[i]);
    unsigned w0 = *(const unsigned*)(h8 + ((unsigned)(s0 << 8) + l4));
    float a0 = al[(i - beg) * 8 + hd2];
    f32x2 lo = __builtin_amdgcn_cvt_pk_f32_fp8(w0, false);
    f32x2 hi = __builtin_amdgcn_cvt_pk_f32_fp8(w0, true);
    acc.x += a0 * lo[0]; acc.y += a0 * lo[1]; acc.z += a0 * hi[0]; acc.w += a0 * hi[1];
  }
  for (; i < end; ++i) {                       // rare deg>DCAP fallback
    int s0 = __builtin_amdgcn_readfirstlane(csr[i]);
    float u0 = as1n[(unsigned)(s0 * 8) + hd2];
    unsigned w0 = *(const unsigned*)(h8 + ((unsigned)(s0 << 8) + l4));
    float a0 = __expf(lrelu(u0 + adv2) - m2) * rden2;
    f32x2 lo = __builtin_amdgcn_cvt_pk_f32_fp8(w0, false);
    f32x2 hi = __builtin_amdgcn_cvt_pk_f32_fp8(w0, true);
    acc.x += a0 * lo[0]; acc.y += a0 * lo[1]; acc.z += a0 * hi[0]; acc.w += a0 * hi[1];
  }
  float4 bv = *(const float4*)(b + l4);
  acc.x += bv.x; acc.y += bv.y; acc.z += bv.z; acc.w += bv.w;
  acc.x = acc.x > 0.f ? acc.x : expm1f(acc.x);
  acc.y = acc.y > 0.f ? acc.y : expm1f(acc.y);
  acc.z = acc.z > 0.f ? acc.z : expm1f(acc.z);
  acc.w = acc.w > 0.f ? acc.w : expm1f(acc.w);
  {
    ushort4 o;
    o.x = f2bu(acc.x); o.y = f2bu(acc.y); o.z = f2bu(acc.z); o.w = f2bu(acc.w);
    *(ushort4*)&xs[w * 256 + l4] = o;
  }
  __syncthreads();
  if (w == 0) {     // gemm2 phase: 16-node tile @ K=256 -> 32 ch + a_s/a_d
    const int nloc = lane & 15;
    const int node2 = n0 + nloc;
    const int ch_base = (lane >> 4) * 4;
    float sA = 0.f, sD = 0.f;
    #pragma unroll
    for (int mf = 0; mf < 2; ++mf) {
      f32x4 c2 = {0.f, 0.f, 0.f, 0.f};
      #pragma unroll
      for (int kk = 0; kk < 8; ++kk) {
        bf16x8 bfr = *(const bf16x8*)&xs[nloc * 256 + kk * 32 + (lane >> 4) * 8];
        c2 = __builtin_amdgcn_mfma_f32_16x16x32_bf16(W2f[(mf * 8 + kk) * 64 + lane],
                                                     bfr, c2, 0, 0, 0);
      }
      float4 av = *(const float4*)(as2 + mf * 16 + ch_base);
      float4 dv = *(const float4*)(ad2 + mf * 16 + ch_base);
      float ps = c2[0] * av.x + c2[1] * av.y + c2[2] * av.z + c2[3] * av.w;
      float pd = c2[0] * dv.x + c2[1] * dv.y + c2[2] * dv.z + c2[3] * dv.w;
      ps += __shfl_xor(ps, 16); ps += __shfl_xor(ps, 32);
      pd += __shfl_xor(pd, 16); pd += __shfl_xor(pd, 32);
      sA += ps; sD += pd;
      ushort4 o;
      o.x = f2bu(c2[0]); o.y = f2bu(c2[1]); o.z = f2bu(c2[2]); o.w = f2bu(c2[3]);
      *(ushort4*)&h2[(unsigned)(node2 * 32 + mf * 16 + ch_base)] = o;
    }
    if (lane < 16) { a_s2o[node2] = sA; a_d2o[node2] = sD; }
  }
}

// Layer-2: fused softmax + gather + bias + ELU + gemm3 (+layer-3 a_s/a_d
// epilogue into fresh buffers). 512 threads = 16 half-waves = 16 nodes/block.
__global__ __launch_bounds__(512) void k_gather2f(const int* __restrict__ rowptr,
                                                  const int* __restrict__ csr,
                                                  const float* __restrict__ a_s,
                                                  const float* __restrict__ a_d,
                                                  const unsigned short* __restrict__ h,
                                                  const float* __restrict__ b,
                                                  const bf16x8* __restrict__ W3f,
                                                  const float* __restrict__ as3,
                                                  const float* __restrict__ ad3,
                                                  unsigned short* __restrict__ h3,
                                                  float* __restrict__ a_s3o,
                                                  float* __restrict__ a_d3o) {
  __shared__ __align__(16) unsigned short xs[16 * 32];
  const int tid = threadIdx.x;
  const int hw = tid >> 5, lane32 = tid & 31;
  const int n0 = blockIdx.x * 16;
  const int node = n0 + hw;
  const int beg = rowptr[node], end = rowptr[node + 1];
  const float adv = a_d[node];

  float mx = -FNEG, sm = 0.f;
  for (int i = beg + lane32; i < end; i += 32) {
    float v = lrelu(a_s[csr[i]] + adv);
    float nm = fmaxf(mx, v);
    sm = sm * __expf(mx - nm) + __expf(v - nm);
    mx = nm;
  }
  #pragma unroll
  for (int off = 1; off < 32; off <<= 1) {
    float mo = __shfl_xor(mx, off, 32);
    float so = __shfl_xor(sm, off, 32);
    float nm = fmaxf(mx, mo);
    sm = sm * __expf(mx - nm) + so * __expf(mo - nm);
    mx = nm;
  }
  float rden = 1.0f / sm;

  float acc = 0.f;
  int i = beg;
  for (; i + 4 <= end; i += 4) {
    int s0 = csr[i], s1 = csr[i + 1], s2 = csr[i + 2], s3 = csr[i + 3];
    float a0 = __expf(lrelu(a_s[s0] + adv) - mx) * rden;
    float a1 = __expf(lrelu(a_s[s1] + adv) - mx) * rden;
    float a2 = __expf(lrelu(a_s[s2] + adv) - mx) * rden;
    float a3 = __expf(lrelu(a_s[s3] + adv) - mx) * rden;
    unsigned short v0 = h[(unsigned)(s0 * 32 + lane32)];
    unsigned short v1 = h[(unsigned)(s1 * 32 + lane32)];
    unsigned short v2 = h[(unsigned)(s2 * 32 + lane32)];
    unsigned short v3 = h[(unsigned)(s3 * 32 + lane32)];
    acc += a0 * b2f(v0) + a1 * b2f(v1) + a2 * b2f(v2) + a3 * b2f(v3);
  }
  for (; i < end; ++i) {
    int s0 = csr[i];
    float a0 = __expf(lrelu(a_s[s0] + adv) - mx) * rden;
    acc += a0 * b2f(h[(unsigned)(s0 * 32 + lane32)]);
  }
  acc += b[lane32];
  acc = acc > 0.f ? acc : expm1f(acc);
  xs[hw * 32 + lane32] = f2bu(acc);
  __syncthreads();
  if (tid < 64) {   // gemm3 phase: 16-node tile @ K=32 -> 40 ch + a_s/a_d
    const int lane = tid;
    const int nloc = lane & 15;
    const int node3 = n0 + nloc;
    const int ch_base = (lane >> 4) * 4;
    bf16x8 bfr = *(const bf16x8*)&xs[nloc * 32 + (lane >> 4) * 8];
    float sA = 0.f, sD = 0.f;
    #pragma unroll
    for (int mf = 0; mf < 3; ++mf) {
      f32x4 c3 = {0.f, 0.f, 0.f, 0.f};
      c3 = __builtin_amdgcn_mfma_f32_16x16x32_bf16(W3f[mf * 64 + lane], bfr, c3, 0, 0, 0);
      int ch0 = mf * 16 + ch_base;
      float4 av = {0.f, 0.f, 0.f, 0.f}, dv = {0.f, 0.f, 0.f, 0.f};
      if (ch0 < 40) {
        av = *(const float4*)(as3 + ch0);
        dv = *(const float4*)(ad3 + ch0);
      }
      float ps = c3[0] * av.x + c3[1] * av.y + c3[2] * av.z + c3[3] * av.w;
      float pd = c3[0] * dv.x + c3[1] * dv.y + c3[2] * dv.z + c3[3] * dv.w;
      ps += __shfl_xor(ps, 16); ps += __shfl_xor(ps, 32);
      pd += __shfl_xor(pd, 16); pd += __shfl_xor(pd, 32);
      sA += ps; sD += pd;
      if (ch0 < 40) {
        ushort4 o;
        o.x = f2bu(c3[0]); o.y = f2bu(c3[1]); o.z = f2bu(c3[2]); o.w = f2bu(c3[3]);
        *(ushort4*)&h3[(unsigned)(node3 * 40 + ch0)] = o;
      }
    }
    if (lane < 16) { a_s3o[node3] = sA; a_d3o[node3] = sD; }
  }
}

// Layer-3: fused softmax + gather + bias + log_softmax -> f32 out.
__global__ __launch_bounds__(256) void k_gather3f(const int* __restrict__ rowptr,
                                                  const int* __restrict__ csr,
                                                  const float* __restrict__ a_s,
                                                  const float* __restrict__ a_d,
                                                  const unsigned short* __restrict__ h,
                                                  const float* __restrict__ b,
                                                  float* __restrict__ out) {
  const int node = blockIdx.x * 4 + (threadIdx.x >> 6);
  const int lane = threadIdx.x & 63;
  const int beg = __builtin_amdgcn_readfirstlane(rowptr[node]);
  const int end = __builtin_amdgcn_readfirstlane(rowptr[node + 1]);
  const float adv = a_d[node];

  float mx = -FNEG, sm = 0.f;
  for (int i = beg + lane; i < end; i += 64) {
    float v = lrelu(a_s[csr[i]] + adv);
    float nm = fmaxf(mx, v);
    sm = sm * __expf(mx - nm) + __expf(v - nm);
    mx = nm;
  }
  #pragma unroll
  for (int off = 1; off < 64; off <<= 1) {
    float mo = __shfl_xor(mx, off);
    float so = __shfl_xor(sm, off);
    float nm = fmaxf(mx, mo);
    sm = sm * __expf(mx - nm) + so * __expf(mo - nm);
    mx = nm;
  }
  float rden = 1.0f / sm;

  float acc = 0.f;
  int i = beg;
  for (; i + 4 <= end; i += 4) {
    int s0 = __builtin_amdgcn_readfirstlane(csr[i]);
    int s1 = __builtin_amdgcn_readfirstlane(csr[i + 1]);
    int s2 = __builtin_amdgcn_readfirstlane(csr[i + 2]);
    int s3 = __builtin_amdgcn_readfirstlane(csr[i + 3]);
    float a0 = __expf(lrelu(a_s[s0] + adv) - mx) * rden;
    float a1 = __expf(lrelu(a_s[s1] + adv) - mx) * rden;
    float a2 = __expf(lrelu(a_s[s2] + adv) - mx) * rden;
    float a3 = __expf(lrelu(a_s[s3] + adv) - mx) * rden;
    if (lane < 40) {
      unsigned short v0 = h[(unsigned)(s0 * 40 + lane)];
      unsigned short v1 = h[(unsigned)(s1 * 40 + lane)];
      unsigned short v2 = h[(unsigned)(s2 * 40 + lane)];
      unsigned short v3 = h[(unsigned)(s3 * 40 + lane)];
      acc += a0 * b2f(v0) + a1 * b2f(v1) + a2 * b2f(v2) + a3 * b2f(v3);
    }
  }
  for (; i < end; ++i) {
    int s0 = __builtin_amdgcn_readfirstlane(csr[i]);
    float a0 = __expf(lrelu(a_s[s0] + adv) - mx) * rden;
    if (lane < 40) acc += a0 * b2f(h[(unsigned)(s0 * 40 + lane)]);
  }
  float v = (lane < 40) ? acc + b[lane] : -FNEG;
  float vmax = v;
  #pragma unroll
  for (int off = 1; off < 64; off <<= 1) vmax = fmaxf(vmax, __shfl_xor(vmax, off));
  float ex = (lane < 40) ? __expf(v - vmax) : 0.f;
  float es = ex;
  #pragma unroll
  for (int off = 1; off < 64; off <<= 1) es += __shfl_xor(es, off);
  float lse = vmax + __logf(es);
  if (lane < 40) out[(long long)node * 40 + lane] = v - lse;
}

extern "C" void kernel_launch(void* const* d_in, const int* in_sizes, int n_in,
                              void* d_out, int out_size, void* d_ws, size_t ws_size,
                              hipStream_t stream) {
  const float* x   = (const float*)d_in[0];
  const int*   eix = (const int*)d_in[1];
  const float* W1  = (const float*)d_in[2];
  const float* as1 = (const float*)d_in[3];
  const float* ad1 = (const float*)d_in[4];
  const float* b1  = (const float*)d_in[5];
  const float* W2  = (const float*)d_in[6];
  const float* as2 = (const float*)d_in[7];
  const float* ad2 = (const float*)d_in[8];
  const float* b2  = (const float*)d_in[9];
  const float* W3  = (const float*)d_in[10];
  const float* as3 = (const float*)d_in[11];
  const float* ad3 = (const float*)d_in[12];
  const float* b3  = (const float*)d_in[13];
  float* out = (float*)d_out;

  if (ws_size < WS_NEED) {
    k_sentinel<<<(out_size + 255) / 256, 256, 0, stream>>>(out, out_size);
    return;
  }

  char* ws = (char*)d_ws;
  int*    src    = (int*)(ws + SRC_OFF);
  int*    dst    = (int*)(ws + DST_OFF);
  int*    rowptr = (int*)(ws + RP_OFF);
  int*    csr    = (int*)(ws + CSR_OFF);
  unsigned short* W1f = (unsigned short*)(ws + W1F_OFF);
  unsigned short* W2f = (unsigned short*)(ws + W2F_OFF);
  unsigned short* W3f = (unsigned short*)(ws + W3F_OFF);
  int*    bsum   = (int*)(ws + SC_OFF);
  unsigned char*  h1q  = (unsigned char*)(ws + H_OFF);
  unsigned short* h2b  = (unsigned short*)(ws + H2B_OFF);
  unsigned short* h3b  = (unsigned short*)(ws + H3B_OFF);
  float*  aS1    = (float*)(ws + ASN_OFF);
  float*  aD1    = (float*)(ws + ADN_OFF);
  float*  aS2    = (float*)(ws + AS2_OFF);
  float*  aD2    = (float*)(ws + AD2_OFF);
  float*  aS3    = (float*)(ws + AS3_OFF);
  float*  aD3    = (float*)(ws + AD3_OFF);
  int*    cnt8   = (int*)(ws + CNT_OFF);
  int*    rank   = (int*)(ws + RANK_OFF);

  // ---- prep + CSR build (prep_edges overlapped with gemm1 in k_fatA) ----
  hipMemsetAsync(ws + CNT_OFF, 0, 3200000, stream);
  k_prep_w<<<21, 256, 0, stream>>>(W1, W2, W3, W1f, W2f, W3f);
  k_fatA<<<FATA_NB, 256, 0, stream>>>(eix, src, dst, cnt8, rank, x,
                                      (const bf16x8*)W1f, as1, ad1, h1q, aS1, aD1);
  k_scan_a<<<NBSC, 1024, 0, stream>>>(cnt8, rowptr, bsum);
  k_scan_b<<<1, 128, 0, stream>>>(bsum);
  k_scan_c<<<NBSC, 1024, 0, stream>>>(rowptr, bsum);
  k_fill_nr<<<(FILL_CH + 255) / 256, 256, 0, stream>>>(src, dst, rank, cnt8,
                                                       rowptr, csr);

  // ---- layer 1: fused softmax+gather+gemm2 (staged alpha) ----
  k_gather1f<<<NN / 16, 1024, 0, stream>>>(rowptr, csr, aS1, aD1, h1q, b1,
                                           (const bf16x8*)W2f, as2, ad2,
                                           h2b, aS2, aD2);

  // ---- layer 2: fused softmax+gather+gemm3 ----
  k_gather2f<<<NN / 16, 512, 0, stream>>>(rowptr, csr, aS2, aD2, h2b, b2,
                                          (const bf16x8*)W3f, as3, ad3,
                                          h3b, aS3, aD3);

  // ---- layer 3: fused softmax+gather+log_softmax ----
  k_gather3f<<<NN / 4, 256, 0, stream>>>(rowptr, csr, aS3, aD3, h3b, b3, out);
}

// Round 16
// 388.687 us; speedup vs baseline: 1.2030x; 1.2030x over previous
//
#include <hip/hip_runtime.h>

#define NN 100000
#define NE 1600000
#define ET 1700000        // NE + NN self-loops
#define NEG 0.2f
#define FNEG 3.4e38f
#define NBSC 98           // scan blocks: ceil(NN/1024)
#define GEMM1_NB 1563     // ceil(NN/64)
#define PE_NB 6641        // ceil(ET/256)
#define FATA_NB 8305      // 5 * 1661 covers 4:1 interleave of PE_NB:GEMM1_NB
#define FILL_CH 425000    // ET/4 (divisible by 8)

// ---------------- workspace layout (bytes) ----------------
#define SRC_OFF   0ULL
#define DST_OFF   6800000ULL
#define RP_OFF    13600000ULL         // rowptr (NN+1)*4
#define CSR_OFF   14400128ULL         // ET*4
#define W1F_OFF   21200128ULL         // 65536  (16mf x 4kk x 64lane x 8 bf16)
#define W2F_OFF   21265664ULL         // 16384
#define W3F_OFF   21282048ULL         // 3072
#define SC_OFF    21285120ULL         // 1024 (block sums)
#define H_OFF     21286144ULL         // h1 as fp8 e4m3: N*256 = 25.6MB
#define H2B_OFF   72486144ULL         // h2b 6.4MB (bf16)
#define H3B_OFF   88486144ULL         // h3b 8MB (bf16)
#define AS3_OFF   123686144ULL        // layer-3 a_s: 400KB
#define AD3_OFF   124086144ULL        // layer-3 a_d: 400KB
#define ASN_OFF   150886144ULL        // layer-1 a_s: 3.2MB
#define ADN_OFF   154086144ULL        // layer-1 a_d: 3.2MB
#define AS2_OFF   157286144ULL        // layer-2 a_s: 400KB
#define AD2_OFF   157686144ULL        // layer-2 a_d: 400KB
#define CNT_OFF   158086144ULL        // region-replicated histogram 8*NN*4 = 3.2MB
#define RANK_OFF  164486144ULL        // per-edge rank within replica: ET*4
#define WS_NEED   171286144ULL

typedef short bf16x8 __attribute__((ext_vector_type(8)));
typedef float f32x4 __attribute__((ext_vector_type(4)));
typedef float f32x2 __attribute__((ext_vector_type(2)));

__device__ __forceinline__ float lrelu(float x) { return x > 0.f ? x : NEG * x; }
__device__ __forceinline__ float b2f(unsigned short u) {
  return __uint_as_float(((unsigned)u) << 16);
}
__device__ __forceinline__ unsigned short f2bu(float f) {   // RNE f32->bf16
  unsigned u = __float_as_uint(f);
  return (unsigned short)((u + 0x7FFFu + ((u >> 16) & 1u)) >> 16);
}

__global__ __launch_bounds__(256) void k_sentinel(float* out, int n) {
  int i = blockIdx.x * 256 + threadIdx.x;
  if (i < n) out[i] = 12345.0f;
}

// Pre-arrange W1/W2/W3 (f32) into MFMA A-fragment order as bf16.
__global__ __launch_bounds__(256) void k_prep_w(const float* __restrict__ W1,
                                                const float* __restrict__ W2,
                                                const float* __restrict__ W3,
                                                unsigned short* __restrict__ W1f,
                                                unsigned short* __restrict__ W2f,
                                                unsigned short* __restrict__ W3f) {
  int idx = blockIdx.x * 256 + threadIdx.x;
  if (idx < 4096) {                       // W1: 16 mf x 4 kk
    int fg = idx >> 6, lane = idx & 63;
    int mf = fg >> 2, kk = fg & 3;
    int c = mf * 16 + (lane & 15), k0 = kk * 32 + (lane >> 4) * 8;
    unsigned short* o = W1f + idx * 8;
    #pragma unroll
    for (int j = 0; j < 8; ++j) o[j] = f2bu(W1[(k0 + j) * 256 + c]);
  } else if (idx < 5120) {                // W2: 2 mf x 8 kk
    int t = idx - 4096;
    int fg = t >> 6, lane = t & 63;
    int mf = fg >> 3, kk = fg & 7;
    int c = mf * 16 + (lane & 15), k0 = kk * 32 + (lane >> 4) * 8;
    unsigned short* o = W2f + t * 8;
    #pragma unroll
    for (int j = 0; j < 8; ++j) o[j] = f2bu(W2[(k0 + j) * 32 + c]);
  } else if (idx < 5312) {                // W3: 3 mf x 1 kk (pad ch>=40 with 0)
    int t = idx - 5120;
    int mf = t >> 6, lane = t & 63;
    int c = mf * 16 + (lane & 15), k0 = (lane >> 4) * 8;
    unsigned short* o = W3f + t * 8;
    #pragma unroll
    for (int j = 0; j < 8; ++j) o[j] = (c < 40) ? f2bu(W3[(k0 + j) * 40 + c]) : 0;
  }
}

// Fat kernel A: prep_edges (+region-replicated deg count, rank capture)
// interleaved 4:1 with gemm1 (h1 = x@W1 -> fp8 e4m3 + fused a_s/a_d in f32).
__global__ __launch_bounds__(256) void k_fatA(const int* __restrict__ raw,
                                              int* __restrict__ src,
                                              int* __restrict__ dst,
                                              int* __restrict__ cnt8,
                                              int* __restrict__ rank,
                                              const float* __restrict__ x,
                                              const bf16x8* __restrict__ W1f,
                                              const float* __restrict__ as1,
                                              const float* __restrict__ ad1,
                                              unsigned char* __restrict__ h8,
                                              float* __restrict__ a_s,
                                              float* __restrict__ a_d) {
  __shared__ __align__(16) unsigned short xs[64 * 128];
  __shared__ float asL[256], adL[256];
  const int bid = blockIdx.x;
  const int grp = bid / 5, rem = bid - grp * 5;
  const int tid = threadIdx.x;

  if (rem != 4) {                               // ---- prep_edges ----
    int pe = grp * 4 + rem;
    if (pe >= PE_NB) return;
    bool is64 = true;
    #pragma unroll
    for (int i = 1; i < 32; i += 2) is64 = is64 && (raw[i] == 0);
    long long e = (long long)pe * 256 + tid;
    if (e >= ET) return;
    int s, d;
    if (e < NE) {
      if (is64) {
        const long long* r = (const long long*)raw;
        s = (int)r[e];
        d = (int)r[NE + e];
      } else {
        s = raw[e];
        d = raw[NE + e];
      }
    } else {
      s = d = (int)(e - NE);
    }
    src[e] = s;
    dst[e] = d;
    rank[e] = atomicAdd(&cnt8[(tid & 7) * NN + d], 1);
    return;
  }

  // ---- gemm1 ----
  if (grp >= GEMM1_NB) return;
  const int n0 = grp * 64;
  asL[tid] = as1[tid];
  adL[tid] = ad1[tid];
  for (int j = tid; j < 2048; j += 256) {       // stage x -> bf16 LDS
    int r = j >> 5;
    int c4 = (j & 31) << 2;
    long long row = n0 + r; if (row >= NN) row = NN - 1;
    float4 v = *(const float4*)(x + row * 128 + c4);
    unsigned short* p = &xs[r * 128 + c4];
    p[0] = f2bu(v.x); p[1] = f2bu(v.y); p[2] = f2bu(v.z); p[3] = f2bu(v.w);
  }
  __syncthreads();
  const int w = tid >> 6, lane = tid & 63;
  const int nloc = w * 16 + (lane & 15);
  const int node = n0 + nloc;
  bf16x8 bfr[4];
  #pragma unroll
  for (int kk = 0; kk < 4; ++kk)
    bfr[kk] = *(const bf16x8*)&xs[nloc * 128 + kk * 32 + (lane >> 4) * 8];
  const int ch_base = (lane >> 4) * 4;
  float sA[8] = {}, sD[8] = {};
  #pragma unroll
  for (int mf = 0; mf < 16; ++mf) {
    f32x4 acc = {0.f, 0.f, 0.f, 0.f};
    #pragma unroll
    for (int kk = 0; kk < 4; ++kk) {
      bf16x8 af = W1f[(mf * 4 + kk) * 64 + lane];
      acc = __builtin_amdgcn_mfma_f32_16x16x32_bf16(af, bfr[kk], acc, 0, 0, 0);
    }
    const float* av = &asL[mf * 16 + ch_base];
    const float* dv = &adL[mf * 16 + ch_base];
    float ps = acc[0] * av[0] + acc[1] * av[1] + acc[2] * av[2] + acc[3] * av[3];
    float pd = acc[0] * dv[0] + acc[1] * dv[1] + acc[2] * dv[2] + acc[3] * dv[3];
    ps += __shfl_xor(ps, 16); ps += __shfl_xor(ps, 32);
    pd += __shfl_xor(pd, 16); pd += __shfl_xor(pd, 32);
    sA[mf >> 1] += ps; sD[mf >> 1] += pd;
    if (node < NN) {
      int w01 = __builtin_amdgcn_cvt_pk_fp8_f32(acc[0], acc[1], 0, false);
      int w0123 = __builtin_amdgcn_cvt_pk_fp8_f32(acc[2], acc[3], w01, true);
      *(unsigned*)&h8[(unsigned)(node * 256 + mf * 16 + ch_base)] = (unsigned)w0123;
    }
  }
  if (lane < 16 && node < NN) {
    #pragma unroll
    for (int hd = 0; hd < 8; ++hd) {
      a_s[node * 8 + hd] = sA[hd];
      a_d[node * 8 + hd] = sD[hd];
    }
  }
}

// Block-level inclusive scan over node degrees, folding the 8 region replicas.
__global__ __launch_bounds__(1024) void k_scan_a(int* __restrict__ cnt8,
                                                 int* __restrict__ rowptr,
                                                 int* __restrict__ bsum) {
  __shared__ int wsum[16];
  const int lane = threadIdx.x & 63, wid = threadIdx.x >> 6;
  int i = blockIdx.x * 1024 + threadIdx.x;
  int x = 0;
  if (i < NN) {
    int run = 0;
    #pragma unroll
    for (int k = 0; k < 8; ++k) {
      int c = cnt8[k * NN + i];
      cnt8[k * NN + i] = run;
      run += c;
    }
    x = run;
  }
  int inc = x;
  #pragma unroll
  for (int off = 1; off < 64; off <<= 1) {
    int t = __shfl_up(inc, off);
    if (lane >= off) inc += t;
  }
  if (lane == 63) wsum[wid] = inc;
  __syncthreads();
  if (wid == 0) {
    int w = (lane < 16) ? wsum[lane] : 0;
    #pragma unroll
    for (int off = 1; off < 16; off <<= 1) {
      int t = __shfl_up(w, off);
      if (lane >= off) w += t;
    }
    if (lane < 16) wsum[lane] = w;
  }
  __syncthreads();
  int base = wid ? wsum[wid - 1] : 0;
  if (i < NN) rowptr[i + 1] = base + inc;
  if (threadIdx.x == 1023) bsum[blockIdx.x] = base + inc;
}

// Exclusive scan of NBSC block sums (in place).
__global__ __launch_bounds__(128) void k_scan_b(int* __restrict__ bsum) {
  __shared__ int w0tot;
  int tid = threadIdx.x;
  int v = (tid < NBSC) ? bsum[tid] : 0;
  int inc = v;
  #pragma unroll
  for (int off = 1; off < 64; off <<= 1) {
    int t = __shfl_up(inc, off);
    if ((tid & 63) >= off) inc += t;
  }
  if (tid == 63) w0tot = inc;
  __syncthreads();
  if (tid >= 64) inc += w0tot;
  if (tid < NBSC) bsum[tid] = inc - v;
}

__global__ __launch_bounds__(1024) void k_scan_c(int* __restrict__ rowptr,
                                                 const int* __restrict__ bsum) {
  int i = blockIdx.x * 1024 + threadIdx.x;
  if (i < NN) rowptr[i + 1] += bsum[blockIdx.x];
  if (i == 0) rowptr[0] = 0;
}

// Atomic-free CSR fill: slot = rowptr[d] + prefix8[e&7][d] + rank[e].
__global__ __launch_bounds__(256) void k_fill_nr(const int* __restrict__ src,
                                                 const int* __restrict__ dst,
                                                 const int* __restrict__ rank,
                                                 const int* __restrict__ cnt8,
                                                 const int* __restrict__ rowptr,
                                                 int* __restrict__ csr) {
  int gid = blockIdx.x * 256 + threadIdx.x;
  if (gid >= FILL_CH) return;
  const int h = gid & 7;
  int e0 = gid, e1 = gid + FILL_CH, e2 = gid + 2 * FILL_CH, e3 = gid + 3 * FILL_CH;
  int d0 = dst[e0], d1 = dst[e1], d2 = dst[e2], d3 = dst[e3];
  int r0 = rank[e0], r1 = rank[e1], r2 = rank[e2], r3 = rank[e3];
  int s0 = src[e0], s1 = src[e1], s2 = src[e2], s3 = src[e3];
  int p0 = cnt8[h * NN + d0], p1 = cnt8[h * NN + d1];
  int p2 = cnt8[h * NN + d2], p3 = cnt8[h * NN + d3];
  int b0 = rowptr[d0], b1 = rowptr[d1], b2 = rowptr[d2], b3 = rowptr[d3];
  csr[b0 + p0 + r0] = s0;
  csr[b1 + p1 + r1] = s1;
  csr[b2 + p2 + r2] = s2;
  csr[b3 + p3 + r3] = s3;
}

// Layer-1: FUSED softmax + fp8 gather + bias + ELU + gemm2 (+layer-2 a_s/a_d
// epilogue). 1024 threads = 16 waves = 16 nodes/block.
// Alpha redundancy fix WITHOUT LDS: in each 8-edge block, lane l computes ONE
// alpha (edge i+(l&7), head l>>3) and lanes fetch the 8 they need via __shfl.
__global__ __launch_bounds__(1024) void k_gather1f(const int* __restrict__ rowptr,
                                                   const int* __restrict__ csr,
                                                   const float* __restrict__ as1n,
                                                   const float* __restrict__ ad1n,
                                                   const unsigned char* __restrict__ h8,
                                                   const float* __restrict__ b,
                                                   const bf16x8* __restrict__ W2f,
                                                   const float* __restrict__ as2,
                                                   const float* __restrict__ ad2,
                                                   unsigned short* __restrict__ h2,
                                                   float* __restrict__ a_s2o,
                                                   float* __restrict__ a_d2o) {
  __shared__ __align__(16) unsigned short xs[16 * 256];   // 8KB only
  const int tid = threadIdx.x;
  const int w = tid >> 6, lane = tid & 63;
  const int n0 = blockIdx.x * 16;
  const int node = n0 + w;
  const int beg = __builtin_amdgcn_readfirstlane(rowptr[node]);
  const int end = __builtin_amdgcn_readfirstlane(rowptr[node + 1]);

  // ---- pass 1: per-head online max/sum (hd = lane&7, edge-group = lane>>3) ----
  const int hd = lane & 7;
  const int eg = lane >> 3;
  const float adv1 = ad1n[node * 8 + hd];
  float mx = -FNEG, sm = 0.f;
  for (int i = beg + eg; i < end; i += 8) {
    float v = lrelu(as1n[csr[i] * 8 + hd] + adv1);
    float nm = fmaxf(mx, v);
    sm = sm * __expf(mx - nm) + __expf(v - nm);
    mx = nm;
  }
  #pragma unroll
  for (int off = 8; off < 64; off <<= 1) {
    float mo = __shfl_xor(mx, off);
    float so = __shfl_xor(sm, off);
    float nm = fmaxf(mx, mo);
    sm = sm * __expf(mx - nm) + so * __expf(mo - nm);
    mx = nm;
  }
  // per-lane head constants (head = lane>>3)
  const int hd2 = lane >> 3;
  const float m2 = __shfl(mx, hd2);
  const float rden2 = 1.0f / __shfl(sm, hd2);
  const float adv2 = ad1n[node * 8 + hd2];

  // ---- pass 2: fp8 gather; alpha computed once per (edge,head) + shuffled ----
  const unsigned l4 = lane * 4;
  const int le = lane & 7;          // which edge of the 8-block this lane owns
  const int grpb = lane & 56;       // hd2*8: shuffle group base
  float4 acc = {0.f, 0.f, 0.f, 0.f};
  int i = beg;
  for (; i + 8 <= end; i += 8) {
    int s0 = __builtin_amdgcn_readfirstlane(csr[i]);
    int s1 = __builtin_amdgcn_readfirstlane(csr[i + 1]);
    int s2 = __builtin_amdgcn_readfirstlane(csr[i + 2]);
    int s3 = __builtin_amdgcn_readfirstlane(csr[i + 3]);
    int s4 = __builtin_amdgcn_readfirstlane(csr[i + 4]);
    int s5 = __builtin_amdgcn_readfirstlane(csr[i + 5]);
    int s6 = __builtin_amdgcn_readfirstlane(csr[i + 6]);
    int s7 = __builtin_amdgcn_readfirstlane(csr[i + 7]);
    // one alpha per lane: edge i+le, head hd2
    int sv = csr[i + le];
    float uv = as1n[(unsigned)(sv * 8) + hd2];
    float aval = __expf(lrelu(uv + adv2) - m2) * rden2;
    float a0 = __shfl(aval, grpb + 0);
    float a1 = __shfl(aval, grpb + 1);
    float a2 = __shfl(aval, grpb + 2);
    float a3 = __shfl(aval, grpb + 3);
    float a4 = __shfl(aval, grpb + 4);
    float a5 = __shfl(aval, grpb + 5);
    float a6 = __shfl(aval, grpb + 6);
    float a7 = __shfl(aval, grpb + 7);
    unsigned w0 = *(const unsigned*)(h8 + ((unsigned)(s0 << 8) + l4));
    unsigned w1 = *(const unsigned*)(h8 + ((unsigned)(s1 << 8) + l4));
    unsigned w2 = *(const unsigned*)(h8 + ((unsigned)(s2 << 8) + l4));
    unsigned w3 = *(const unsigned*)(h8 + ((unsigned)(s3 << 8) + l4));
    unsigned w4 = *(const unsigned*)(h8 + ((unsigned)(s4 << 8) + l4));
    unsigned w5 = *(const unsigned*)(h8 + ((unsigned)(s5 << 8) + l4));
    unsigned w6 = *(const unsigned*)(h8 + ((unsigned)(s6 << 8) + l4));
    unsigned w7 = *(const unsigned*)(h8 + ((unsigned)(s7 << 8) + l4));
    f32x2 lo, hi;
    lo = __builtin_amdgcn_cvt_pk_f32_fp8(w0, false); hi = __builtin_amdgcn_cvt_pk_f32_fp8(w0, true);
    acc.x += a0 * lo[0]; acc.y += a0 * lo[1]; acc.z += a0 * hi[0]; acc.w += a0 * hi[1];
    lo = __builtin_amdgcn_cvt_pk_f32_fp8(w1, false); hi = __builtin_amdgcn_cvt_pk_f32_fp8(w1, true);
    acc.x += a1 * lo[0]; acc.y += a1 * lo[1]; acc.z += a1 * hi[0]; acc.w += a1 * hi[1];
    lo = __builtin_amdgcn_cvt_pk_f32_fp8(w2, false); hi = __builtin_amdgcn_cvt_pk_f32_fp8(w2, true);
    acc.x += a2 * lo[0]; acc.y += a2 * lo[1]; acc.z += a2 * hi[0]; acc.w += a2 * hi[1];
    lo = __builtin_amdgcn_cvt_pk_f32_fp8(w3, false); hi = __builtin_amdgcn_cvt_pk_f32_fp8(w3, true);
    acc.x += a3 * lo[0]; acc.y += a3 * lo[1]; acc.z += a3 * hi[0]; acc.w += a3 * hi[1];
    lo = __builtin_amdgcn_cvt_pk_f32_fp8(w4, false); hi = __builtin_amdgcn_cvt_pk_f32_fp8(w4, true);
    acc.x += a4 * lo[0]; acc.y += a4 * lo[1]; acc.z += a4 * hi[0]; acc.w += a4 * hi[1];
    lo = __builtin_amdgcn_cvt_pk_f32_fp8(w5, false); hi = __builtin_amdgcn_cvt_pk_f32_fp8(w5, true);
    acc.x += a5 * lo[0]; acc.y += a5 * lo[1]; acc.z += a5 * hi[0]; acc.w += a5 * hi[1];
    lo = __builtin_amdgcn_cvt_pk_f32_fp8(w6, false); hi = __builtin_amdgcn_cvt_pk_f32_fp8(w6, true);
    acc.x += a6 * lo[0]; acc.y += a6 * lo[1]; acc.z += a6 * hi[0]; acc.w += a6 * hi[1];
    lo = __builtin_amdgcn_cvt_pk_f32_fp8(w7, false); hi = __builtin_amdgcn_cvt_pk_f32_fp8(w7, true);
    acc.x += a7 * lo[0]; acc.y += a7 * lo[1]; acc.z += a7 * hi[0]; acc.w += a7 * hi[1];
  }
  for (; i < end; ++i) {                   // tail: per-lane inline alpha
    int s0 = __builtin_amdgcn_readfirstlane(csr[i]);
    float u0 = as1n[(unsigned)(s0 * 8) + hd2];
    unsigned w0 = *(const unsigned*)(h8 + ((unsigned)(s0 << 8) + l4));
    float a0 = __expf(lrelu(u0 + adv2) - m2) * rden2;
    f32x2 lo = __builtin_amdgcn_cvt_pk_f32_fp8(w0, false);
    f32x2 hi = __builtin_amdgcn_cvt_pk_f32_fp8(w0, true);
    acc.x += a0 * lo[0]; acc.y += a0 * lo[1]; acc.z += a0 * hi[0]; acc.w += a0 * hi[1];
  }
  float4 bv = *(const float4*)(b + l4);
  acc.x += bv.x; acc.y += bv.y; acc.z += bv.z; acc.w += bv.w;
  acc.x = acc.x > 0.f ? acc.x : expm1f(acc.x);
  acc.y = acc.y > 0.f ? acc.y : expm1f(acc.y);
  acc.z = acc.z > 0.f ? acc.z : expm1f(acc.z);
  acc.w = acc.w > 0.f ? acc.w : expm1f(acc.w);
  {
    ushort4 o;
    o.x = f2bu(acc.x); o.y = f2bu(acc.y); o.z = f2bu(acc.z); o.w = f2bu(acc.w);
    *(ushort4*)&xs[w * 256 + l4] = o;
  }
  __syncthreads();
  if (w == 0) {     // gemm2 phase: 16-node tile @ K=256 -> 32 ch + a_s/a_d
    const int nloc = lane & 15;
    const int node2 = n0 + nloc;
    const int ch_base = (lane >> 4) * 4;
    float sA = 0.f, sD = 0.f;
    #pragma unroll
    for (int mf = 0; mf < 2; ++mf) {
      f32x4 c2 = {0.f, 0.f, 0.f, 0.f};
      #pragma unroll
      for (int kk = 0; kk < 8; ++kk) {
        bf16x8 bfr = *(const bf16x8*)&xs[nloc * 256 + kk * 32 + (lane >> 4) * 8];
        c2 = __builtin_amdgcn_mfma_f32_16x16x32_bf16(W2f[(mf * 8 + kk) * 64 + lane],
                                                     bfr, c2, 0, 0, 0);
      }
      float4 av = *(const float4*)(as2 + mf * 16 + ch_base);
      float4 dv = *(const float4*)(ad2 + mf * 16 + ch_base);
      float ps = c2[0] * av.x + c2[1] * av.y + c2[2] * av.z + c2[3] * av.w;
      float pd = c2[0] * dv.x + c2[1] * dv.y + c2[2] * dv.z + c2[3] * dv.w;
      ps += __shfl_xor(ps, 16); ps += __shfl_xor(ps, 32);
      pd += __shfl_xor(pd, 16); pd += __shfl_xor(pd, 32);
      sA += ps; sD += pd;
      ushort4 o;
      o.x = f2bu(c2[0]); o.y = f2bu(c2[1]); o.z = f2bu(c2[2]); o.w = f2bu(c2[3]);
      *(ushort4*)&h2[(unsigned)(node2 * 32 + mf * 16 + ch_base)] = o;
    }
    if (lane < 16) { a_s2o[node2] = sA; a_d2o[node2] = sD; }
  }
}

// Layer-2: fused softmax + gather + bias + ELU + gemm3 (+layer-3 a_s/a_d
// epilogue into fresh buffers). 512 threads = 16 half-waves = 16 nodes/block.
__global__ __launch_bounds__(512) void k_gather2f(const int* __restrict__ rowptr,
                                                  const int* __restrict__ csr,
                                                  const float* __restrict__ a_s,
                                                  const float* __restrict__ a_d,
                                                  const unsigned short* __restrict__ h,
                                                  const float* __restrict__ b,
                                                  const bf16x8* __restrict__ W3f,
                                                  const float* __restrict__ as3,
                                                  const float* __restrict__ ad3,
                                                  unsigned short* __restrict__ h3,
                                                  float* __restrict__ a_s3o,
                                                  float* __restrict__ a_d3o) {
  __shared__ __align__(16) unsigned short xs[16 * 32];
  const int tid = threadIdx.x;
  const int hw = tid >> 5, lane32 = tid & 31;
  const int n0 = blockIdx.x * 16;
  const int node = n0 + hw;
  const int beg = rowptr[node], end = rowptr[node + 1];
  const float adv = a_d[node];

  float mx = -FNEG, sm = 0.f;
  for (int i = beg + lane32; i < end; i += 32) {
    float v = lrelu(a_s[csr[i]] + adv);
    float nm = fmaxf(mx, v);
    sm = sm * __expf(mx - nm) + __expf(v - nm);
    mx = nm;
  }
  #pragma unroll
  for (int off = 1; off < 32; off <<= 1) {
    float mo = __shfl_xor(mx, off, 32);
    float so = __shfl_xor(sm, off, 32);
    float nm = fmaxf(mx, mo);
    sm = sm * __expf(mx - nm) + so * __expf(mo - nm);
    mx = nm;
  }
  float rden = 1.0f / sm;

  float acc = 0.f;
  int i = beg;
  for (; i + 4 <= end; i += 4) {
    int s0 = csr[i], s1 = csr[i + 1], s2 = csr[i + 2], s3 = csr[i + 3];
    float a0 = __expf(lrelu(a_s[s0] + adv) - mx) * rden;
    float a1 = __expf(lrelu(a_s[s1] + adv) - mx) * rden;
    float a2 = __expf(lrelu(a_s[s2] + adv) - mx) * rden;
    float a3 = __expf(lrelu(a_s[s3] + adv) - mx) * rden;
    unsigned short v0 = h[(unsigned)(s0 * 32 + lane32)];
    unsigned short v1 = h[(unsigned)(s1 * 32 + lane32)];
    unsigned short v2 = h[(unsigned)(s2 * 32 + lane32)];
    unsigned short v3 = h[(unsigned)(s3 * 32 + lane32)];
    acc += a0 * b2f(v0) + a1 * b2f(v1) + a2 * b2f(v2) + a3 * b2f(v3);
  }
  for (; i < end; ++i) {
    int s0 = csr[i];
    float a0 = __expf(lrelu(a_s[s0] + adv) - mx) * rden;
    acc += a0 * b2f(h[(unsigned)(s0 * 32 + lane32)]);
  }
  acc += b[lane32];
  acc = acc > 0.f ? acc : expm1f(acc);
  xs[hw * 32 + lane32] = f2bu(acc);
  __syncthreads();
  if (tid < 64) {   // gemm3 phase: 16-node tile @ K=32 -> 40 ch + a_s/a_d
    const int lane = tid;
    const int nloc = lane & 15;
    const int node3 = n0 + nloc;
    const int ch_base = (lane >> 4) * 4;
    bf16x8 bfr = *(const bf16x8*)&xs[nloc * 32 + (lane >> 4) * 8];
    float sA = 0.f, sD = 0.f;
    #pragma unroll
    for (int mf = 0; mf < 3; ++mf) {
      f32x4 c3 = {0.f, 0.f, 0.f, 0.f};
      c3 = __builtin_amdgcn_mfma_f32_16x16x32_bf16(W3f[mf * 64 + lane], bfr, c3, 0, 0, 0);
      int ch0 = mf * 16 + ch_base;
      float4 av = {0.f, 0.f, 0.f, 0.f}, dv = {0.f, 0.f, 0.f, 0.f};
      if (ch0 < 40) {
        av = *(const float4*)(as3 + ch0);
        dv = *(const float4*)(ad3 + ch0);
      }
      float ps = c3[0] * av.x + c3[1] * av.y + c3[2] * av.z + c3[3] * av.w;
      float pd = c3[0] * dv.x + c3[1] * dv.y + c3[2] * dv.z + c3[3] * dv.w;
      ps += __shfl_xor(ps, 16); ps += __shfl_xor(ps, 32);
      pd += __shfl_xor(pd, 16); pd += __shfl_xor(pd, 32);
      sA += ps; sD += pd;
      if (ch0 < 40) {
        ushort4 o;
        o.x = f2bu(c3[0]); o.y = f2bu(c3[1]); o.z = f2bu(c3[2]); o.w = f2bu(c3[3]);
        *(ushort4*)&h3[(unsigned)(node3 * 40 + ch0)] = o;
      }
    }
    if (lane < 16) { a_s3o[node3] = sA; a_d3o[node3] = sD; }
  }
}

// Layer-3: fused softmax + gather + bias + log_softmax -> f32 out.
__global__ __launch_bounds__(256) void k_gather3f(const int* __restrict__ rowptr,
                                                  const int* __restrict__ csr,
                                                  const float* __restrict__ a_s,
                                                  const float* __restrict__ a_d,
                                                  const unsigned short* __restrict__ h,
                                                  const float* __restrict__ b,
                                                  float* __restrict__ out) {
  const int node = blockIdx.x * 4 + (threadIdx.x >> 6);
  const int lane = threadIdx.x & 63;
  const int beg = __builtin_amdgcn_readfirstlane(rowptr[node]);
  const int end = __builtin_amdgcn_readfirstlane(rowptr[node + 1]);
  const float adv = a_d[node];

  float mx = -FNEG, sm = 0.f;
  for (int i = beg + lane; i < end; i += 64) {
    float v = lrelu(a_s[csr[i]] + adv);
    float nm = fmaxf(mx, v);
    sm = sm * __expf(mx - nm) + __expf(v - nm);
    mx = nm;
  }
  #pragma unroll
  for (int off = 1; off < 64; off <<= 1) {
    float mo = __shfl_xor(mx, off);
    float so = __shfl_xor(sm, off);
    float nm = fmaxf(mx, mo);
    sm = sm * __expf(mx - nm) + so * __expf(mo - nm);
    mx = nm;
  }
  float rden = 1.0f / sm;

  float acc = 0.f;
  int i = beg;
  for (; i + 4 <= end; i += 4) {
    int s0 = __builtin_amdgcn_readfirstlane(csr[i]);
    int s1 = __builtin_amdgcn_readfirstlane(csr[i + 1]);
    int s2 = __builtin_amdgcn_readfirstlane(csr[i + 2]);
    int s3 = __builtin_amdgcn_readfirstlane(csr[i + 3]);
    float a0 = __expf(lrelu(a_s[s0] + adv) - mx) * rden;
    float a1 = __expf(lrelu(a_s[s1] + adv) - mx) * rden;
    float a2 = __expf(lrelu(a_s[s2] + adv) - mx) * rden;
    float a3 = __expf(lrelu(a_s[s3] + adv) - mx) * rden;
    if (lane < 40) {
      unsigned short v0 = h[(unsigned)(s0 * 40 + lane)];
      unsigned short v1 = h[(unsigned)(s1 * 40 + lane)];
      unsigned short v2 = h[(unsigned)(s2 * 40 + lane)];
      unsigned short v3 = h[(unsigned)(s3 * 40 + lane)];
      acc += a0 * b2f(v0) + a1 * b2f(v1) + a2 * b2f(v2) + a3 * b2f(v3);
    }
  }
  for (; i < end; ++i) {
    int s0 = __builtin_amdgcn_readfirstlane(csr[i]);
    float a0 = __expf(lrelu(a_s[s0] + adv) - mx) * rden;
    if (lane < 40) acc += a0 * b2f(h[(unsigned)(s0 * 40 + lane)]);
  }
  float v = (lane < 40) ? acc + b[lane] : -FNEG;
  float vmax = v;
  #pragma unroll
  for (int off = 1; off < 64; off <<= 1) vmax = fmaxf(vmax, __shfl_xor(vmax, off));
  float ex = (lane < 40) ? __expf(v - vmax) : 0.f;
  float es = ex;
  #pragma unroll
  for (int off = 1; off < 64; off <<= 1) es += __shfl_xor(es, off);
  float lse = vmax + __logf(es);
  if (lane < 40) out[(long long)node * 40 + lane] = v - lse;
}

extern "C" void kernel_launch(void* const* d_in, const int* in_sizes, int n_in,
                              void* d_out, int out_size, void* d_ws, size_t ws_size,
                              hipStream_t stream) {
  const float* x   = (const float*)d_in[0];
  const int*   eix = (const int*)d_in[1];
  const float* W1  = (const float*)d_in[2];
  const float* as1 = (const float*)d_in[3];
  const float* ad1 = (const float*)d_in[4];
  const float* b1  = (const float*)d_in[5];
  const float* W2  = (const float*)d_in[6];
  const float* as2 = (const float*)d_in[7];
  const float* ad2 = (const float*)d_in[8];
  const float* b2  = (const float*)d_in[9];
  const float* W3  = (const float*)d_in[10];
  const float* as3 = (const float*)d_in[11];
  const float* ad3 = (const float*)d_in[12];
  const float* b3  = (const float*)d_in[13];
  float* out = (float*)d_out;

  if (ws_size < WS_NEED) {
    k_sentinel<<<(out_size + 255) / 256, 256, 0, stream>>>(out, out_size);
    return;
  }

  char* ws = (char*)d_ws;
  int*    src    = (int*)(ws + SRC_OFF);
  int*    dst    = (int*)(ws + DST_OFF);
  int*    rowptr = (int*)(ws + RP_OFF);
  int*    csr    = (int*)(ws + CSR_OFF);
  unsigned short* W1f = (unsigned short*)(ws + W1F_OFF);
  unsigned short* W2f = (unsigned short*)(ws + W2F_OFF);
  unsigned short* W3f = (unsigned short*)(ws + W3F_OFF);
  int*    bsum   = (int*)(ws + SC_OFF);
  unsigned char*  h1q  = (unsigned char*)(ws + H_OFF);
  unsigned short* h2b  = (unsigned short*)(ws + H2B_OFF);
  unsigned short* h3b  = (unsigned short*)(ws + H3B_OFF);
  float*  aS1    = (float*)(ws + ASN_OFF);
  float*  aD1    = (float*)(ws + ADN_OFF);
  float*  aS2    = (float*)(ws + AS2_OFF);
  float*  aD2    = (float*)(ws + AD2_OFF);
  float*  aS3    = (float*)(ws + AS3_OFF);
  float*  aD3    = (float*)(ws + AD3_OFF);
  int*    cnt8   = (int*)(ws + CNT_OFF);
  int*    rank   = (int*)(ws + RANK_OFF);

  // ---- prep + CSR build (prep_edges overlapped with gemm1 in k_fatA) ----
  hipMemsetAsync(ws + CNT_OFF, 0, 3200000, stream);
  k_prep_w<<<21, 256, 0, stream>>>(W1, W2, W3, W1f, W2f, W3f);
  k_fatA<<<FATA_NB, 256, 0, stream>>>(eix, src, dst, cnt8, rank, x,
                                      (const bf16x8*)W1f, as1, ad1, h1q, aS1, aD1);
  k_scan_a<<<NBSC, 1024, 0, stream>>>(cnt8, rowptr, bsum);
  k_scan_b<<<1, 128, 0, stream>>>(bsum);
  k_scan_c<<<NBSC, 1024, 0, stream>>>(rowptr, bsum);
  k_fill_nr<<<(FILL_CH + 255) / 256, 256, 0, stream>>>(src, dst, rank, cnt8,
                                                       rowptr, csr);

  // ---- layer 1: fused softmax+gather+gemm2 (shuffle-shared alpha) ----
  k_gather1f<<<NN / 16, 1024, 0, stream>>>(rowptr, csr, aS1, aD1, h1q, b1,
                                           (const bf16x8*)W2f, as2, ad2,
                                           h2b, aS2, aD2);

  // ---- layer 2: fused softmax+gather+gemm3 ----
  k_gather2f<<<NN / 16, 512, 0, stream>>>(rowptr, csr, aS2, aD2, h2b, b2,
                                          (const bf16x8*)W3f, as3, ad3,
                                          h3b, aS3, aD3);

  // ---- layer 3: fused softmax+gather+log_softmax ----
  k_gather3f<<<NN / 4, 256, 0, stream>>>(rowptr, csr, aS3, aD3, h3b, b3, out);
}